// Round 1
// 1253.038 us; speedup vs baseline: 1.0926x; 1.0926x over previous
//
#include <hip/hip_runtime.h>
#include <float.h>

#define NEMB 1024
#define EDIM 256
#define BM   64
#define HW   4096   // 64*64
#define NB   16
#define NT   1024   // threads/block: 16 waves share one 64 KiB z tile
#define NW   (NT / 64)
#define ZQ_ELEMS 33554432   // 32*256*4096

// numpy FLOAT_pairwise_sum of squares, n=256: two 128-blocks, 8 accumulators
// r[j] += a[8i+j], tree-combine ((r0+r1)+(r2+r3))+((r4+r5)+(r6+r7)), then
// blk0+blk1. Squares rounded separately (contract off).
template <typename F>
__device__ __forceinline__ float np_sumsq_256(F get) {
#pragma clang fp contract(off)
    float blk[2];
#pragma unroll
    for (int h = 0; h < 2; ++h) {
        const int base = h * 128;
        float r[8];
#pragma unroll
        for (int j = 0; j < 8; ++j) {
            float v = get(base + j);
            r[j] = v * v;
        }
        for (int i = 8; i < 128; i += 8) {
#pragma unroll
            for (int j = 0; j < 8; ++j) {
                float v = get(base + i + j);
                float p = v * v;
                r[j] = r[j] + p;
            }
        }
        blk[h] = ((r[0] + r[1]) + (r[2] + r[3])) + ((r[4] + r[5]) + (r[6] + r[7]));
    }
    return blk[0] + blk[1];
}

__global__ __launch_bounds__(256) void esq_kernel(const float* __restrict__ emb,
                                                  float* __restrict__ esq) {
    int n = blockIdx.x * 256 + threadIdx.x;
    const float* e = emb + (size_t)n * EDIM;
    esq[n] = np_sumsq_256([&](int k) { return e[k]; });
}

// z tile, PAIR-INTERLEAVED: value z(k,r) at word (k>>1)*128 + 2*r + (k&1).
// - main-loop read: lane r reads float2 {z(2m,r), z(2m+1,r)} at word m*128+2r.
//   The 64 lanes cover words [m*128, m*128+128) exactly -> 4 accesses/bank =
//   BW floor -> conflict-free ds_read_b64 (half the LDS issue cost of the old
//   k-major per-k ds_read_b32, which oversubscribed LDS issue ~1.45x).
// - staging write: a global float4 (4 consecutive rows, one k) scatters at
//   word stride 2 (ds_write2-able); transient ~8-way conflict but staging is
//   ~4% of main-loop LDS traffic.
__global__ __launch_bounds__(NT, 8) void vq_kernel(const float* __restrict__ z,
                                                   const float* __restrict__ emb,
                                                   const float* __restrict__ esq,
                                                   float* __restrict__ out) {
    __shared__ float zl[BM * EDIM];   // 64 KiB -> 2 blocks/CU, 32 waves/CU

    const int t   = threadIdx.x;
    const int blk = blockIdx.x;           // 2048 blocks: 64 per batch image
    const int b   = blk >> 6;
    const int hw0 = (blk & 63) * BM;
    const float* zb = z + (size_t)b * EDIM * HW;

    // ---- stage z tile: 4096 float4, 4 per thread, coalesced along hw ----
#pragma unroll
    for (int pass = 0; pass < 4; ++pass) {
        int f4 = pass * NT + t;
        int r4 = (f4 & 15) * 4;
        int k  = f4 >> 4;
        float4 v = *(const float4*)(zb + (size_t)k * HW + hw0 + r4);
        int w = (k >> 1) * 128 + 2 * r4 + (k & 1);
        zl[w + 0] = v.x;
        zl[w + 2] = v.y;
        zl[w + 4] = v.z;
        zl[w + 6] = v.w;
    }
    __syncthreads();

    const int r = t & 63;                 // my row (lane id)
    const float* zr = zl + 2 * r;         // lane's row base in interleaved tile
    // z_sq with exact numpy pairwise semantics (redundant per wave; cheap)
    const float zsq = np_sumsq_256([&](int k) { return zr[(k >> 1) * 128 + (k & 1)]; });

    // wave id -> 64-codeword range (uniform -> scalar emb loads)
    const int q = __builtin_amdgcn_readfirstlane(t >> 6);

    float best = FLT_MAX;
    int   bidx = 0;
#pragma unroll 1
    for (int g = 0; g < 4; ++g) {
        const int n0 = q * 64 + g * NB;
        float acc[NB];
#pragma unroll
        for (int j = 0; j < NB; ++j) acc[j] = 0.f;

        // e_z: strictly sequential fp32 FMA over k=0..255 per codeword
        // (numpy/BLAS microkernel order — interleaving j between instructions
        // does not change each acc[j]'s own summation order, so distances are
        // bit-identical). k-loop unrolled x2 with two float2 z register
        // buffers so next chunk's ds_read_b64s overlap current FMAs.
        // NB=16 halves LDS reads per FMA vs NB=8; j in half-blocks of 8 keeps
        // <=8 s_load_dwordx8 of emb in flight (SGPR budget).
        float2 zk[4], zk2[4];
#pragma unroll
        for (int u = 0; u < 4; ++u) zk[u] = *(const float2*)(zr + u * 128);
        for (int k = 0; k < EDIM; k += 16) {
#pragma unroll
            for (int u = 0; u < 4; ++u)
                zk2[u] = *(const float2*)(zr + ((k + 8) >> 1) * 128 + u * 128);
#pragma unroll
            for (int jh = 0; jh < 2; ++jh) {
                const float* eb = emb + (size_t)(n0 + jh * 8) * EDIM + k;
#pragma unroll
                for (int u = 0; u < 8; ++u) {
                    const float zv = (u & 1) ? zk[u >> 1].y : zk[u >> 1].x;
#pragma unroll
                    for (int j2 = 0; j2 < 8; ++j2)
                        acc[jh * 8 + j2] = fmaf(zv, eb[(size_t)j2 * EDIM + u],
                                                acc[jh * 8 + j2]);
                }
            }
            if (k + 16 < EDIM) {
#pragma unroll
                for (int u = 0; u < 4; ++u)
                    zk[u] = *(const float2*)(zr + ((k + 16) >> 1) * 128 + u * 128);
            }
#pragma unroll
            for (int jh = 0; jh < 2; ++jh) {
                const float* eb = emb + (size_t)(n0 + jh * 8) * EDIM + k + 8;
#pragma unroll
                for (int u = 0; u < 8; ++u) {
                    const float zv = (u & 1) ? zk2[u >> 1].y : zk2[u >> 1].x;
#pragma unroll
                    for (int j2 = 0; j2 < 8; ++j2)
                        acc[jh * 8 + j2] = fmaf(zv, eb[(size_t)j2 * EDIM + u],
                                                acc[jh * 8 + j2]);
                }
            }
        }
#pragma unroll
        for (int j = 0; j < NB; ++j) {
            // numpy: dist = RN( RN(zsq+esq) - 2*ez ); 2*ez exact -> fma form
            // is bit-identical.
            float t1 = zsq + esq[n0 + j];
            float d  = fmaf(-2.f, acc[j], t1);
            if (d < best) { best = d; bidx = n0 + j; }   // strict <: first-index
        }
    }

    // ---- cross-wave (min,idx) reduction, reusing zl ----
    __syncthreads();                        // all zl reads done
    float* rv   = zl;                       // [1024] best value
    int*   ri   = (int*)(zl + NT);          // [1024] best idx
    int*   ifin = (int*)(zl + 2 * NT);      // [64]   final idx per row
    rv[t] = best;
    ri[t] = bidx;
    __syncthreads();
    if (t < 64) {
        float bv = rv[t];
        int   bi = ri[t];
#pragma unroll
        for (int w = 1; w < NW; ++w) {
            float v = rv[t + 64 * w];
            int   i = ri[t + 64 * w];
            // waves cover ascending idx ranges; strict < keeps lowest idx
            if (v < bv) { bv = v; bi = i; }
        }
        ifin[t] = bi;
        out[(size_t)ZQ_ELEMS + (size_t)blk * BM + t] = (float)bi;  // idx as float
    }
    __syncthreads();

    // ---- z_q[b][c][hw] = emb[idx[hw]][c], coalesced float4 along hw ----
    float* zq = out + (size_t)b * EDIM * HW;
#pragma unroll
    for (int pass = 0; pass < 4; ++pass) {
        int f4 = pass * NT + t;
        int r4 = (f4 & 15) * 4;
        int c  = f4 >> 4;
        float4 v;
        v.x = emb[(size_t)ifin[r4 + 0] * EDIM + c];
        v.y = emb[(size_t)ifin[r4 + 1] * EDIM + c];
        v.z = emb[(size_t)ifin[r4 + 2] * EDIM + c];
        v.w = emb[(size_t)ifin[r4 + 3] * EDIM + c];
        *(float4*)(zq + (size_t)c * HW + hw0 + r4) = v;
    }
}

extern "C" void kernel_launch(void* const* d_in, const int* in_sizes, int n_in,
                              void* d_out, int out_size, void* d_ws, size_t ws_size,
                              hipStream_t stream) {
    const float* z   = (const float*)d_in[0];   // [32,256,64,64]
    const float* emb = (const float*)d_in[1];   // [1024,256]
    float* out = (float*)d_out;                 // 33554432 z_q + 131072 idx (as float)
    float* esq = (float*)d_ws;                  // 1024 floats scratch

    esq_kernel<<<NEMB / 256, 256, 0, stream>>>(emb, esq);
    vq_kernel<<<131072 / BM, NT, 0, stream>>>(z, emb, esq, out);
}